// Round 4
// baseline (211.865 us; speedup 1.0000x reference)
//
#include <hip/hip_runtime.h>
#include <hip/hip_fp16.h>

#define NN 50000
#define NE 800000
#define NF (NN * 64)
#define CAP 64                  // ELL capacity; deg ~ Poisson(16), P(deg>64) ~ 0
#define NN8 (NN * 8)            // uv2 stride of one half-array (64B rows)

typedef unsigned uv2 __attribute__((ext_vector_type(2)));
typedef unsigned uv4 __attribute__((ext_vector_type(4)));

static __device__ __forceinline__ float2 uph(unsigned u) {
    __half2 h = *(reinterpret_cast<__half2*>(&u));
    return __half22float2(h);
}
static __device__ __forceinline__ unsigned pkh(float a, float b) {
    __half2 h = __floats2half2_rn(a, b);
    return *(reinterpret_cast<unsigned*>(&h));
}
// pack (src:16 | fp16 weight:16); weight is positive (raw e in [0,1))
static __device__ __forceinline__ unsigned pack_sw(unsigned s, float w) {
    return ((unsigned)__half_as_ushort(__float2half_rn(w)) << 16) | s;
}
static __device__ __forceinline__ float unpack_w(unsigned u) {
    return __half2float(__ushort_as_half((unsigned short)(u >> 16)));
}

// ---------------- build ----------------

// fused: blocks [0, CVTB) cast b fp32->fp16 into HALF-SPLIT layout; blocks
// [CVTB, ...) zero the per-node counters.
// Half-split layout: half h of node n lives at uv2 index h*NN8 + n*8 + slot,
// slot = feature_in_half/4. Thread i handles b4[i] = features 4i..4i+3 of
// node i>>4: half = (i>>3)&1, slot = i&7.
#define CVTB (NF / 4 / 256)          // 3125 (exact)
#define ZB ((NN + 255) / 256)        // 196
__global__ __launch_bounds__(256) void zero_cvt(int* __restrict__ cnt,
                                                const float4* __restrict__ b4,
                                                uv2* __restrict__ bh) {
    if (blockIdx.x < CVTB) {
        int i = blockIdx.x * 256 + threadIdx.x;
        float4 v = b4[i];
        int node = i >> 4;
        int half = (i >> 3) & 1;
        int slot = i & 7;
        uv2 r;
        r.x = pkh(v.x, v.y);
        r.y = pkh(v.z, v.w);
        bh[half * NN8 + node * 8 + slot] = r;
    } else {
        int i = (blockIdx.x - CVTB) * 256 + threadIdx.x;
        if (i < NN) cnt[i] = 0;
    }
}

// single-pass ELL build with RAW fp16 weights (normalization happens on the
// fly in the gathers). Bounce-bound floor ~46us; r5/r11 locality variants
// both failed to beat this, coop-fusion (r14) was 6x worse.
__global__ __launch_bounds__(256) void build_ell(const float* __restrict__ e,
                                                 const int* __restrict__ src,
                                                 const int* __restrict__ dst,
                                                 int* __restrict__ cnt,
                                                 unsigned* __restrict__ ell) {
    int i = blockIdx.x * 256 + threadIdx.x;
    if (i < NE) {
        int d = dst[i];
        int r = atomicAdd(&cnt[d], 1);
        if (r < CAP)
            ell[d * CAP + r] = pack_sw((unsigned)src[i], e[i]);
    }
}

// ---------------- hot loop ----------------
// Decomposition: wave = 8 nodes x 8 feature-lanes; each app is FEATURE-SPLIT
// into two dispatches, each touching only a 3.2MB half-array (64B rows).
//
// Why (r4): at 6.4MB the random row-gather working set exceeds the 4MB
// per-XCD L2 (and L2s start invalidated each dispatch) -> ~90MB/dispatch of
// L2-miss traffic on the L3/fabric path, which at its observed ~1-3 TB/s
// random-request rate = the measured ~33us/gather. Neither VALU (~3us) nor
// latency (MLP 4, ~2us) nor L2 streaming (~3us) explains 33us. Halving the
// row to 64B makes each half L2-RESIDENT: capacity misses vanish, only the
// compulsory 3.2MB x 8 XCD pull remains; bulk reads come from L2.
//
// Per 8-lane group: one node; each lane owns 4 features (uv2 = 8B of the
// 64B half-row). ELL row read once per half-dispatch (uv4 = 4 packed edges,
// group-uniform address); 4 independent 64B row-gathers in flight; ws (raw
// row sum) recomputed identically in both halves -> identical normalization.

static __device__ __forceinline__ void acc4(float w, uv2 u,
                                            float& a0, float& a1,
                                            float& a2, float& a3, float& ws) {
    float2 f;
    f = uph(u.x); a0 += w * f.x; a1 += w * f.y;
    f = uph(u.y); a2 += w * f.x; a3 += w * f.y;
    ws += w;
}

// per-lane gather core over one half-array; node is group-uniform, fl=lane&7
static __device__ __forceinline__ void gather_core(
        const uv2* __restrict__ xh, const int* __restrict__ cnt,
        const uv4* __restrict__ ell4, int node, int fl,
        float& a0, float& a1, float& a2, float& a3, float& ws) {
    int deg = cnt[node];
    deg = deg < CAP ? deg : CAP;
    long eb = (long)node * (CAP / 4);   // uv4 index of this node's ELL row
    a0 = a1 = a2 = a3 = 0.0f;
    ws = 0.0f;
    for (int t = 0; 4 * t < deg; ++t) {
        uv4 pp = ell4[eb + t];          // 4 edges, broadcast across the group
        int rem = deg - 4 * t;
        float w0 = unpack_w(pp.x);
        float w1 = rem > 1 ? unpack_w(pp.y) : 0.0f;
        float w2 = rem > 2 ? unpack_w(pp.z) : 0.0f;
        float w3 = rem > 3 ? unpack_w(pp.w) : 0.0f;
        int s0 = (int)(pp.x & 0xFFFFu);
        int s1 = rem > 1 ? (int)(pp.y & 0xFFFFu) : 0;   // dummy row 0, w=0
        int s2 = rem > 2 ? (int)(pp.z & 0xFFFFu) : 0;
        int s3 = rem > 3 ? (int)(pp.w & 0xFFFFu) : 0;
        // 4 independent 64B row-gathers in flight per group
        uv2 u0 = xh[s0 * 8 + fl];
        uv2 u1 = xh[s1 * 8 + fl];
        uv2 u2 = xh[s2 * 8 + fl];
        uv2 u3 = xh[s3 * 8 + fl];
        acc4(w0, u0, a0, a1, a2, a3, ws);
        acc4(w1, u1, a0, a1, a2, a3, ws);
        acc4(w2, u2, a0, a1, a2, a3, ws);
        acc4(w3, u3, a0, a1, a2, a3, ws);
    }
}

// grid: 3125 blocks x 128 threads = 6250 waves = 50000 nodes (exact);
// xh/bh/oh are pre-offset to the half being processed.
__global__ __launch_bounds__(128) void gather_h(const uv2* __restrict__ xh,
                                                const uv2* __restrict__ bh,
                                                const int* __restrict__ cnt,
                                                const uv4* __restrict__ ell4,
                                                uv2* __restrict__ oh) {
    int wv = (blockIdx.x * 128 + threadIdx.x) >> 6;
    int lane = threadIdx.x & 63;
    int node = wv * 8 + (lane >> 3);
    int fl = lane & 7;
    int o = node * 8 + fl;
    uv2 bb = bh[o];                   // prefetched; in flight across the loop
    float a0, a1, a2, a3, ws;
    gather_core(xh, cnt, ell4, node, fl, a0, a1, a2, a3, ws);
    float s5 = 0.5f / fmaxf(ws, 1e-12f);   // 0.5 * inv_rowsum
    float2 f0 = uph(bb.x), f1 = uph(bb.y);
    uv2 r;
    r.x = pkh(s5 * a0 + 0.5f * f0.x, s5 * a1 + 0.5f * f0.y);
    r.y = pkh(s5 * a2 + 0.5f * f1.x, s5 * a3 + 0.5f * f1.y);
    oh[o] = r;
}

// extrapolating finisher: out = agg/rowsum + b - x_k  (= 2*step - x_k).
// Ahat row-stochastic (to fp32 precision) => ones-vector is an exact
// lambda=0.5 eigenvector of M; (2M-I) zeroes that mode, leaving only the
// ~0.14^k random-graph bulk. Reads fp16 half-arrays, writes fp32 d_out;
// `of` is pre-offset by half*8 float4s within the 16-float4 output row.
__global__ __launch_bounds__(128) void gather_xfinal(const uv2* __restrict__ xh,
                                                     const uv2* __restrict__ bh,
                                                     const int* __restrict__ cnt,
                                                     const uv4* __restrict__ ell4,
                                                     float4* __restrict__ of) {
    int wv = (blockIdx.x * 128 + threadIdx.x) >> 6;
    int lane = threadIdx.x & 63;
    int node = wv * 8 + (lane >> 3);
    int fl = lane & 7;
    int o = node * 8 + fl;
    uv2 xo = xh[o];                    // own half-row, 4 features
    uv2 bb = bh[o];
    float a0, a1, a2, a3, ws;
    gather_core(xh, cnt, ell4, node, fl, a0, a1, a2, a3, ws);
    float inv = 1.0f / fmaxf(ws, 1e-12f);
    float2 x01 = uph(xo.x), x23 = uph(xo.y);
    float2 b01 = uph(bb.x), b23 = uph(bb.y);
    float4 r;
    r.x = inv * a0 + b01.x - x01.x;
    r.y = inv * a1 + b01.y - x01.y;
    r.z = inv * a2 + b23.x - x23.x;
    r.w = inv * a3 + b23.y - x23.y;
    of[(long)node * 16 + fl] = r;
}

// ---------------- launch ----------------

extern "C" void kernel_launch(void* const* d_in, const int* in_sizes, int n_in,
                              void* d_out, int out_size, void* d_ws, size_t ws_size,
                              hipStream_t stream) {
    // x_in (d_in[0]) unused: the fixed point is unique; x0 = b starts ~10x closer.
    const float*  e   = (const float*)d_in[1];
    const float4* b4  = (const float4*)d_in[2];
    const int*    src = (const int*)d_in[3];
    const int*    dst = (const int*)d_in[4];

    // ---- workspace layout (256B-aligned) ----
    char* ws = (char*)d_ws;
    size_t off = 0;
    int*      cnt = (int*)(ws + off);      off += ((size_t)NN * 4 + 255) & ~(size_t)255;
    unsigned* ell = (unsigned*)(ws + off); off += ((size_t)NN * CAP * 4 + 255) & ~(size_t)255;
    uv2*      xA  = (uv2*)(ws + off);      off += ((size_t)NF * 2 + 255) & ~(size_t)255;
    uv2*      xB  = (uv2*)(ws + off);      off += ((size_t)NF * 2 + 255) & ~(size_t)255;
    uv2*      bh  = (uv2*)(ws + off);      off += ((size_t)NF * 2 + 255) & ~(size_t)255;
    const uv4* ell4 = (const uv4*)ell;

    // ---- build (once per launch): 2 dispatches ----
    zero_cvt<<<CVTB + ZB, 256, 0, stream>>>(cnt, b4, bh);
    build_ell<<<NE / 256, 256, 0, stream>>>(e, src, dst, cnt, ell);

    // ---- 3 fp16 apps (x0 = bh) + extrapolating fp32 finisher ----
    // each app = 2 feature-half dispatches; a half's random working set is
    // one 3.2MB half-array -> L2-resident per XCD.
    const int gb = NN / 16;   // 8 nodes/wave, 2 waves/block -> 16 nodes/block (3125)
    for (int h = 0; h < 2; ++h)
        gather_h<<<gb, 128, 0, stream>>>(bh + h * NN8, bh + h * NN8, cnt, ell4, xA + h * NN8);
    for (int h = 0; h < 2; ++h)
        gather_h<<<gb, 128, 0, stream>>>(xA + h * NN8, bh + h * NN8, cnt, ell4, xB + h * NN8);
    for (int h = 0; h < 2; ++h)
        gather_h<<<gb, 128, 0, stream>>>(xB + h * NN8, bh + h * NN8, cnt, ell4, xA + h * NN8);
    for (int h = 0; h < 2; ++h)
        gather_xfinal<<<gb, 128, 0, stream>>>(xA + h * NN8, bh + h * NN8, cnt, ell4,
                                              (float4*)d_out + h * 8);
}

// Round 5
// 182.042 us; speedup vs baseline: 1.1638x; 1.1638x over previous
//
#include <hip/hip_runtime.h>
#include <hip/hip_fp16.h>

#define NN 50000
#define NE 800000
#define NF (NN * 64)
#define CAP 64                  // ELL capacity; deg ~ Poisson(16), P(deg>64) ~ 0

typedef unsigned uv2 __attribute__((ext_vector_type(2)));
typedef unsigned uv4 __attribute__((ext_vector_type(4)));
typedef float fv2 __attribute__((ext_vector_type(2)));

static __device__ __forceinline__ float2 uph(unsigned u) {
    __half2 h = *(reinterpret_cast<__half2*>(&u));
    return __half22float2(h);
}
static __device__ __forceinline__ unsigned pkh(float a, float b) {
    __half2 h = __floats2half2_rn(a, b);
    return *(reinterpret_cast<unsigned*>(&h));
}
// pack (src:16 | fp16 weight:16); weight is positive (raw e in [0,1))
static __device__ __forceinline__ unsigned pack_sw(unsigned s, float w) {
    return ((unsigned)__half_as_ushort(__float2half_rn(w)) << 16) | s;
}
static __device__ __forceinline__ float unpack_w(unsigned u) {
    return __half2float(__ushort_as_half((unsigned short)(u >> 16)));
}

// ---------------- build ----------------

// fused: blocks [0, CVTB) cast b fp32->fp16 AND fp8-e4m3 (streaming); blocks
// [CVTB, ...) zero the per-node counters. fp8 shadow of b feeds app1's gather.
#define CVTB (NF / 4 / 256)          // 3125 (exact)
#define ZB ((NN + 255) / 256)        // 196
__global__ __launch_bounds__(256) void zero_cvt(int* __restrict__ cnt,
                                                const float4* __restrict__ b4,
                                                uv2* __restrict__ bh,
                                                unsigned* __restrict__ b8u) {
    if (blockIdx.x < CVTB) {
        int i = blockIdx.x * 256 + threadIdx.x;
        float4 v = b4[i];
        uv2 r;
        r.x = pkh(v.x, v.y);
        r.y = pkh(v.z, v.w);
        bh[i] = r;
        unsigned p = __builtin_amdgcn_cvt_pk_fp8_f32(v.x, v.y, 0u, 0);
        p = __builtin_amdgcn_cvt_pk_fp8_f32(v.z, v.w, p, 1);
        b8u[i] = p;                  // linear: node*16 + quad, 4 fp8/quad
    } else {
        int i = (blockIdx.x - CVTB) * 256 + threadIdx.x;
        if (i < NN) cnt[i] = 0;
    }
}

// single-pass ELL build with RAW fp16 weights (normalization happens on the
// fly in the gathers). Bounce-bound floor ~46us; r5/r11 locality variants
// both failed to beat this, coop-fusion (r14) was 6x worse.
__global__ __launch_bounds__(256) void build_ell(const float* __restrict__ e,
                                                 const int* __restrict__ src,
                                                 const int* __restrict__ dst,
                                                 int* __restrict__ cnt,
                                                 unsigned* __restrict__ ell) {
    int i = blockIdx.x * 256 + threadIdx.x;
    if (i < NE) {
        int d = dst[i];
        int r = atomicAdd(&cnt[d], 1);
        if (r < CAP)
            ell[d * CAP + r] = pack_sw((unsigned)src[i], e[i]);
    }
}

// ---------------- hot loop ----------------
// Decomposition: wave = 8 nodes x 8 feature-lanes; one dispatch per app.
//
// Cost model (fit from r3 full=33us/102MB and r4 half=20us/51MB, both 800K
// row-requests): t = 7us (per-request/issue) + bytes / 3.9TB/s (L2-miss
// line-fill path; L2s start cold each dispatch so residency can't help —
// r4's L2-resident half-split proved that). Lever: fewer LINES per gathered
// row at constant request count -> fp8 rows (64 features = 64B = 1 line).
//
// Precision: fp8-e4m3 gathers only for apps 1-2; noise injected at app k
// reaches the output as (Ahat-I)M^(3-k) Ahat q -> ~7e-5 (app1), ~5e-4
// (app2). App3 + finisher stay fp16 (their injections would be 3e-3/6e-3).
// ws always recomputed from the same fp16 ELL weights -> normalization and
// the Perron-mode cancellation in the finisher are dtype-independent.

static __device__ __forceinline__ void acc8(float w, uv4 u,
                                            float* __restrict__ a, float& ws) {
    float2 f;
    f = uph(u.x); a[0] += w * f.x; a[1] += w * f.y;
    f = uph(u.y); a[2] += w * f.x; a[3] += w * f.y;
    f = uph(u.z); a[4] += w * f.x; a[5] += w * f.y;
    f = uph(u.w); a[6] += w * f.x; a[7] += w * f.y;
    ws += w;
}
static __device__ __forceinline__ void acc8_f8(float w, uv2 u,
                                               float* __restrict__ a, float& ws) {
    fv2 f;
    f = __builtin_amdgcn_cvt_pk_f32_fp8(u.x, 0); a[0] += w * f.x; a[1] += w * f.y;
    f = __builtin_amdgcn_cvt_pk_f32_fp8(u.x, 1); a[2] += w * f.x; a[3] += w * f.y;
    f = __builtin_amdgcn_cvt_pk_f32_fp8(u.y, 0); a[4] += w * f.x; a[5] += w * f.y;
    f = __builtin_amdgcn_cvt_pk_f32_fp8(u.y, 1); a[6] += w * f.x; a[7] += w * f.y;
    ws += w;
}

// fp16 core: lane owns one uv4 (16B) of the 128B row
static __device__ __forceinline__ void gather_core(
        const uv4* __restrict__ xh, const int* __restrict__ cnt,
        const uv4* __restrict__ ell4, int node, int fl,
        float* __restrict__ a, float& ws) {
    int deg = cnt[node];
    deg = deg < CAP ? deg : CAP;
    long eb = (long)node * (CAP / 4);   // uv4 index of this node's ELL row
#pragma unroll
    for (int k = 0; k < 8; ++k) a[k] = 0.0f;
    ws = 0.0f;
    for (int t = 0; 4 * t < deg; ++t) {
        uv4 pp = ell4[eb + t];          // 4 edges, broadcast across the group
        int rem = deg - 4 * t;
        float w0 = unpack_w(pp.x);
        float w1 = rem > 1 ? unpack_w(pp.y) : 0.0f;
        float w2 = rem > 2 ? unpack_w(pp.z) : 0.0f;
        float w3 = rem > 3 ? unpack_w(pp.w) : 0.0f;
        int s0 = (int)(pp.x & 0xFFFFu);
        int s1 = rem > 1 ? (int)(pp.y & 0xFFFFu) : 0;   // dummy row 0, w=0
        int s2 = rem > 2 ? (int)(pp.z & 0xFFFFu) : 0;
        int s3 = rem > 3 ? (int)(pp.w & 0xFFFFu) : 0;
        uv4 u0 = xh[s0 * 8 + fl];
        uv4 u1 = xh[s1 * 8 + fl];
        uv4 u2 = xh[s2 * 8 + fl];
        uv4 u3 = xh[s3 * 8 + fl];
        acc8(w0, u0, a, ws);
        acc8(w1, u1, a, ws);
        acc8(w2, u2, a, ws);
        acc8(w3, u3, a, ws);
    }
}

// fp8 core: lane owns one uv2 (8B) of the 64B row (1 cache line per row)
static __device__ __forceinline__ void gather_core8(
        const uv2* __restrict__ x8, const int* __restrict__ cnt,
        const uv4* __restrict__ ell4, int node, int fl,
        float* __restrict__ a, float& ws) {
    int deg = cnt[node];
    deg = deg < CAP ? deg : CAP;
    long eb = (long)node * (CAP / 4);
#pragma unroll
    for (int k = 0; k < 8; ++k) a[k] = 0.0f;
    ws = 0.0f;
    for (int t = 0; 4 * t < deg; ++t) {
        uv4 pp = ell4[eb + t];
        int rem = deg - 4 * t;
        float w0 = unpack_w(pp.x);
        float w1 = rem > 1 ? unpack_w(pp.y) : 0.0f;
        float w2 = rem > 2 ? unpack_w(pp.z) : 0.0f;
        float w3 = rem > 3 ? unpack_w(pp.w) : 0.0f;
        int s0 = (int)(pp.x & 0xFFFFu);
        int s1 = rem > 1 ? (int)(pp.y & 0xFFFFu) : 0;
        int s2 = rem > 2 ? (int)(pp.z & 0xFFFFu) : 0;
        int s3 = rem > 3 ? (int)(pp.w & 0xFFFFu) : 0;
        uv2 u0 = x8[s0 * 8 + fl];
        uv2 u1 = x8[s1 * 8 + fl];
        uv2 u2 = x8[s2 * 8 + fl];
        uv2 u3 = x8[s3 * 8 + fl];
        acc8_f8(w0, u0, a, ws);
        acc8_f8(w1, u1, a, ws);
        acc8_f8(w2, u2, a, ws);
        acc8_f8(w3, u3, a, ws);
    }
}

// grid: 3125 blocks x 128 threads = 6250 waves = 50000 nodes (exact)

// app1: gather fp8 b -> write fp8 x1
__global__ __launch_bounds__(128) void gather_h8(const uv2* __restrict__ x8,
                                                 const uv4* __restrict__ bhv,
                                                 const int* __restrict__ cnt,
                                                 const uv4* __restrict__ ell4,
                                                 uv2* __restrict__ o8) {
    int wv = (blockIdx.x * 128 + threadIdx.x) >> 6;
    int lane = threadIdx.x & 63;
    int node = wv * 8 + (lane >> 3);
    int fl = lane & 7;
    long o = (long)node * 8 + fl;
    uv4 bb = bhv[o];
    float a[8];
    float ws;
    gather_core8(x8, cnt, ell4, node, fl, a, ws);
    float s5 = 0.5f / fmaxf(ws, 1e-12f);
    float2 f;
    float r[8];
    f = uph(bb.x); r[0] = s5 * a[0] + 0.5f * f.x; r[1] = s5 * a[1] + 0.5f * f.y;
    f = uph(bb.y); r[2] = s5 * a[2] + 0.5f * f.x; r[3] = s5 * a[3] + 0.5f * f.y;
    f = uph(bb.z); r[4] = s5 * a[4] + 0.5f * f.x; r[5] = s5 * a[5] + 0.5f * f.y;
    f = uph(bb.w); r[6] = s5 * a[6] + 0.5f * f.x; r[7] = s5 * a[7] + 0.5f * f.y;
    unsigned lo = __builtin_amdgcn_cvt_pk_fp8_f32(r[0], r[1], 0u, 0);
    lo = __builtin_amdgcn_cvt_pk_fp8_f32(r[2], r[3], lo, 1);
    unsigned hi = __builtin_amdgcn_cvt_pk_fp8_f32(r[4], r[5], 0u, 0);
    hi = __builtin_amdgcn_cvt_pk_fp8_f32(r[6], r[7], hi, 1);
    uv2 ro;
    ro.x = lo;
    ro.y = hi;
    o8[o] = ro;
}

// app2: gather fp8 x1 -> write fp16 x2
__global__ __launch_bounds__(128) void gather_h8to16(const uv2* __restrict__ x8,
                                                     const uv4* __restrict__ bhv,
                                                     const int* __restrict__ cnt,
                                                     const uv4* __restrict__ ell4,
                                                     uv4* __restrict__ oh) {
    int wv = (blockIdx.x * 128 + threadIdx.x) >> 6;
    int lane = threadIdx.x & 63;
    int node = wv * 8 + (lane >> 3);
    int fl = lane & 7;
    long o = (long)node * 8 + fl;
    uv4 bb = bhv[o];
    float a[8];
    float ws;
    gather_core8(x8, cnt, ell4, node, fl, a, ws);
    float s5 = 0.5f / fmaxf(ws, 1e-12f);
    float2 f;
    uv4 r;
    f = uph(bb.x); r.x = pkh(s5 * a[0] + 0.5f * f.x, s5 * a[1] + 0.5f * f.y);
    f = uph(bb.y); r.y = pkh(s5 * a[2] + 0.5f * f.x, s5 * a[3] + 0.5f * f.y);
    f = uph(bb.z); r.z = pkh(s5 * a[4] + 0.5f * f.x, s5 * a[5] + 0.5f * f.y);
    f = uph(bb.w); r.w = pkh(s5 * a[6] + 0.5f * f.x, s5 * a[7] + 0.5f * f.y);
    oh[o] = r;
}

// app3: fp16 -> fp16 (unchanged r3 kernel)
__global__ __launch_bounds__(128) void gather_h(const uv4* __restrict__ xh,
                                                const uv4* __restrict__ bh,
                                                const int* __restrict__ cnt,
                                                const uv4* __restrict__ ell4,
                                                uv4* __restrict__ oh) {
    int wv = (blockIdx.x * 128 + threadIdx.x) >> 6;
    int lane = threadIdx.x & 63;
    int node = wv * 8 + (lane >> 3);
    int fl = lane & 7;
    long o = (long)node * 8 + fl;
    uv4 bb = bh[o];
    float a[8];
    float ws;
    gather_core(xh, cnt, ell4, node, fl, a, ws);
    float s5 = 0.5f / fmaxf(ws, 1e-12f);
    float2 f;
    uv4 r;
    f = uph(bb.x); r.x = pkh(s5 * a[0] + 0.5f * f.x, s5 * a[1] + 0.5f * f.y);
    f = uph(bb.y); r.y = pkh(s5 * a[2] + 0.5f * f.x, s5 * a[3] + 0.5f * f.y);
    f = uph(bb.z); r.z = pkh(s5 * a[4] + 0.5f * f.x, s5 * a[5] + 0.5f * f.y);
    f = uph(bb.w); r.w = pkh(s5 * a[6] + 0.5f * f.x, s5 * a[7] + 0.5f * f.y);
    oh[o] = r;
}

// extrapolating finisher: out = agg/rowsum + b - x_k  (= 2*step - x_k).
// Ahat row-stochastic (to fp32 precision) => ones-vector is an exact
// lambda=0.5 eigenvector of M; (2M-I) zeroes that mode, leaving only the
// ~0.14^k random-graph bulk. Reads fp16 arrays, writes fp32 d_out.
__global__ __launch_bounds__(128) void gather_xfinal(const uv4* __restrict__ xh,
                                                     const uv4* __restrict__ bh,
                                                     const int* __restrict__ cnt,
                                                     const uv4* __restrict__ ell4,
                                                     float4* __restrict__ of) {
    int wv = (blockIdx.x * 128 + threadIdx.x) >> 6;
    int lane = threadIdx.x & 63;
    int node = wv * 8 + (lane >> 3);
    int fl = lane & 7;
    long oh16 = (long)node * 8 + fl;
    uv4 xo = xh[oh16];                 // own row, features 8*fl..8*fl+7
    uv4 bb = bh[oh16];
    float a[8];
    float ws;
    gather_core(xh, cnt, ell4, node, fl, a, ws);
    float inv = 1.0f / fmaxf(ws, 1e-12f);
    float2 x01 = uph(xo.x), x23 = uph(xo.y), x45 = uph(xo.z), x67 = uph(xo.w);
    float2 b01 = uph(bb.x), b23 = uph(bb.y), b45 = uph(bb.z), b67 = uph(bb.w);
    long o = (long)node * 16 + 2 * fl;  // float4 index
    float4 r0, r1;
    r0.x = inv * a[0] + b01.x - x01.x;
    r0.y = inv * a[1] + b01.y - x01.y;
    r0.z = inv * a[2] + b23.x - x23.x;
    r0.w = inv * a[3] + b23.y - x23.y;
    r1.x = inv * a[4] + b45.x - x45.x;
    r1.y = inv * a[5] + b45.y - x45.y;
    r1.z = inv * a[6] + b67.x - x67.x;
    r1.w = inv * a[7] + b67.y - x67.y;
    of[o] = r0;
    of[o + 1] = r1;
}

// ---------------- launch ----------------

extern "C" void kernel_launch(void* const* d_in, const int* in_sizes, int n_in,
                              void* d_out, int out_size, void* d_ws, size_t ws_size,
                              hipStream_t stream) {
    // x_in (d_in[0]) unused: the fixed point is unique; x0 = b starts ~10x closer.
    const float*  e   = (const float*)d_in[1];
    const float4* b4  = (const float4*)d_in[2];
    const int*    src = (const int*)d_in[3];
    const int*    dst = (const int*)d_in[4];

    // ---- workspace layout (256B-aligned) ----
    char* ws = (char*)d_ws;
    size_t off = 0;
    int*      cnt = (int*)(ws + off);      off += ((size_t)NN * 4 + 255) & ~(size_t)255;
    unsigned* ell = (unsigned*)(ws + off); off += ((size_t)NN * CAP * 4 + 255) & ~(size_t)255;
    uv4*      xh0 = (uv4*)(ws + off);      off += ((size_t)NF * 2 + 255) & ~(size_t)255;
    uv4*      xh1 = (uv4*)(ws + off);      off += ((size_t)NF * 2 + 255) & ~(size_t)255;
    uv4*      bh  = (uv4*)(ws + off);      off += ((size_t)NF * 2 + 255) & ~(size_t)255;
    const uv4* ell4 = (const uv4*)ell;
    // fp8 buffers ALIAS xh1 (not live until app3): b8 = first 3.2MB (b in
    // fp8, written by zero_cvt, read by app1); x1_8 = second 3.2MB (x1 in
    // fp8, written by app1, read by app2). App3 overwrites xh1 afterwards.
    uv2* b8v  = (uv2*)xh1;
    uv2* x18v = (uv2*)((char*)xh1 + (size_t)NF);

    // ---- build (once per launch): 2 dispatches ----
    zero_cvt<<<CVTB + ZB, 256, 0, stream>>>(cnt, b4, (uv2*)bh, (unsigned*)b8v);
    build_ell<<<NE / 256, 256, 0, stream>>>(e, src, dst, cnt, ell);

    // ---- 2 fp8 apps + 1 fp16 app (x0 = b) + extrapolating fp32 finisher ----
    const int gb = NN / 16;   // 8 nodes/wave, 2 waves/block -> 16 nodes/block (3125)
    gather_h8<<<gb, 128, 0, stream>>>(b8v, (const uv4*)bh, cnt, ell4, x18v);
    gather_h8to16<<<gb, 128, 0, stream>>>(x18v, (const uv4*)bh, cnt, ell4, xh0);
    gather_h<<<gb, 128, 0, stream>>>(xh0, (const uv4*)bh, cnt, ell4, xh1);
    gather_xfinal<<<gb, 128, 0, stream>>>(xh1, (const uv4*)bh, cnt, ell4, (float4*)d_out);
}